// Round 1
// 542.600 us; speedup vs baseline: 1.0169x; 1.0169x over previous
//
#include <hip/hip_runtime.h>
#include <hip/hip_fp16.h>
#include <math.h>

#define HC 16      // hidden
#define INC 128    // in_channels
#define OUTC 32    // out_channels
#define BKT_SHIFT 8            // 256 nodes per bucket
#define CAP 9216               // bucket edge capacity: E[8192] + 11 sigma
#define NBMAX 1024             // max buckets (782 actual)
#define BINS 12512             // edges per bin block (staged fully in LDS)

typedef _Float16 f16;

// ================= CSR build: LDS-staged binning =================

__global__ void init_gcur_kernel(int* __restrict__ gcur, int nbkt) {
    int i = blockIdx.x * blockDim.x + threadIdx.x;
    if (i < nbkt) gcur[i] = i * CAP;
}

// 512 threads/block: same 64KB LDS, 2x the waves for latency hiding vs R4.
// Packed entry: (dlocal << 18) | src   (src < 2^18, dlocal < 256)
__global__ void __launch_bounds__(512) bin_kernel(
        const int* __restrict__ src, const int* __restrict__ dst,
        int* __restrict__ gcur, int* __restrict__ csrbuf, int e, int nbkt) {
    __shared__ int ent[BINS];        // 50 KB staging
    __shared__ int hist[NBMAX];      // counts -> local cursors
    __shared__ int off[NBMAX];       // exclusive offsets into staging
    __shared__ int gbase[NBMAX];     // reserved global bases
    __shared__ int pscan[512];
    int tid = threadIdx.x;
    int beg = blockIdx.x * BINS;
    int end = min(beg + BINS, e);
    int sz = end - beg;
    if (sz <= 0) return;

    for (int i = tid; i < NBMAX; i += 512) hist[i] = 0;
    __syncthreads();
    for (int i = beg + tid; i < end; i += 512)
        atomicAdd(&hist[dst[i] >> BKT_SHIFT], 1);
    __syncthreads();
    // scan: thread t owns buckets 2t, 2t+1
    int b0 = tid * 2;
    int c0 = hist[b0], c1 = hist[b0 + 1];
    int tsum = c0 + c1;
    pscan[tid] = tsum;
    __syncthreads();
    for (int d = 1; d < 512; d <<= 1) {
        int v = (tid >= d) ? pscan[tid - d] : 0;
        __syncthreads();
        pscan[tid] += v;
        __syncthreads();
    }
    int ex = pscan[tid] - tsum;
    off[b0]     = ex;
    off[b0 + 1] = ex + c0;
    if (c0) gbase[b0]     = atomicAdd(&gcur[b0], c0);
    if (c1) gbase[b0 + 1] = atomicAdd(&gcur[b0 + 1], c1);
    hist[b0] = 0; hist[b0 + 1] = 0;
    __syncthreads();
    // group into staging
    for (int i = beg + tid; i < end; i += 512) {
        int d = dst[i];
        int b = d >> BKT_SHIFT;
        int p = off[b] + atomicAdd(&hist[b], 1);
        ent[p] = (src[i] & 0x3FFFF) | ((d & 255) << 18);
    }
    __syncthreads();
    // flush: contiguous k; per-element binary search for bucket
    for (int k0 = 0; k0 < sz; k0 += 512) {
        int k = k0 + tid;
        if (k < sz) {
            int lo = 0, hi = nbkt - 1;     // largest b with off[b] <= k
            while (lo < hi) {
                int mid = (lo + hi + 1) >> 1;
                if (off[mid] <= k) lo = mid; else hi = mid - 1;
            }
            csrbuf[gbase[lo] + (k - off[lo])] = ent[k];
        }
    }
}

// One block (512 threads) per bucket: group entries by node, emit row ranges + dinv.
__global__ void __launch_bounds__(512) bucketize_kernel(
        const int* __restrict__ gcur, int* __restrict__ csrbuf,
        int* __restrict__ row_beg, int* __restrict__ row_end,
        float* __restrict__ dinv, int n) {
    __shared__ int ent[CAP];     // 36 KB
    __shared__ int cnt[256];
    __shared__ int off[256];
    __shared__ int cur[256];
    int tid = threadIdx.x;
    int b = blockIdx.x;
    int base = b * CAP;
    int sz = gcur[b] - base;
    if (sz > CAP) sz = CAP;      // defensive (statically unreachable)
    int node0 = b << BKT_SHIFT;
    int nnodes = min(256, n - node0);
    for (int i = tid; i < sz; i += 512) ent[i] = csrbuf[base + i];
    if (tid < 256) cnt[tid] = 0;
    __syncthreads();
    for (int i = tid; i < sz; i += 512) atomicAdd(&cnt[ent[i] >> 18], 1);
    __syncthreads();
    int v = (tid < 256) ? cnt[tid] : 0;
    if (tid < 256) off[tid] = v;
    __syncthreads();
    for (int d = 1; d < 256; d <<= 1) {
        int u = (tid < 256 && tid >= d) ? off[tid - d] : 0;
        __syncthreads();
        if (tid < 256) off[tid] += u;
        __syncthreads();
    }
    if (tid < 256) {
        int excl = off[tid] - v;
        cur[tid] = excl;
        if (tid < nnodes) {
            row_beg[node0 + tid] = base + excl;
            row_end[node0 + tid] = base + excl + v;
            dinv[node0 + tid] = rsqrtf((float)v + 1.0f);   // +1 self-loop
        }
    }
    __syncthreads();
    for (int i = tid; i < sz; i += 512) {
        int p = ent[i];
        int dl = p >> 18;
        int pos = atomicAdd(&cur[dl], 1);
        csrbuf[base + pos] = p & 0x3FFFF;
    }
}

// ================= layer 1 GEMM: hd1 = (x @ W1) * dinv[node], stored fp16 =====
__global__ void gemm1_kernel(const float* __restrict__ x, const float* __restrict__ W1,
                             const float* __restrict__ dinv, f16* __restrict__ hd1, int n) {
    __shared__ float sW[INC * HC];   // 8 KB
    for (int i = threadIdx.x; i < INC * HC; i += blockDim.x) sW[i] = W1[i];
    __syncthreads();
    int node = blockIdx.x * blockDim.x + threadIdx.x;
    if (node >= n) return;
    const float4* xr = (const float4*)(x + (size_t)node * INC);
    float acc[HC];
#pragma unroll
    for (int f = 0; f < HC; ++f) acc[f] = 0.f;
#pragma unroll 4
    for (int k4 = 0; k4 < INC / 4; ++k4) {
        float4 v = xr[k4];
        const float* w = &sW[k4 * 4 * HC];
#pragma unroll
        for (int f = 0; f < HC; ++f)
            acc[f] += v.x * w[f] + v.y * w[HC + f] + v.z * w[2 * HC + f] + v.w * w[3 * HC + f];
    }
    float di = dinv[node];
    union { f16 h[HC]; float4 q[2]; } u;
#pragma unroll
    for (int f = 0; f < HC; ++f) u.h[f] = (f16)(acc[f] * di);
    float4* hl = (float4*)(hd1 + (size_t)node * HC);
    hl[0] = u.q[0];
    hl[1] = u.q[1];
}

// ===== layer-1 gather + fused W2: agg via grouped rows, epilogue in-wave =====
// lane f of node's 16-lane group holds feature f. After gather:
// h1[f] = relu(acc*di + b1[f]);  hd2[f] = di * sum_k h1[k]*W2[k][f]  (16 shuffles)
__global__ void __launch_bounds__(256) gather_fuse1_kernel(
        const f16* __restrict__ hd1, const int* __restrict__ csr,
        const int* __restrict__ row_beg, const int* __restrict__ row_end,
        const float* __restrict__ dinv, const float* __restrict__ b1,
        const float* __restrict__ W2, f16* __restrict__ hd2, int n) {
    __shared__ float sW[HC * 17];    // pitch 17: conflict-free column reads
    __shared__ float sb[HC];
    if (threadIdx.x < HC * HC) sW[(threadIdx.x >> 4) * 17 + (threadIdx.x & 15)] = W2[threadIdx.x];
    if (threadIdx.x < HC) sb[threadIdx.x] = b1[threadIdx.x];
    __syncthreads();
    int t = blockIdx.x * blockDim.x + threadIdx.x;
    int node = t >> 4;
    if (node >= n) return;
    int f = t & 15;
    int beg = row_beg[node], end = row_end[node];
    float acc = (float)hd1[(size_t)node * HC + f];   // self-loop term
    int j = beg;
    for (; j + 7 < end; j += 8) {
        int s0 = __builtin_nontemporal_load(csr + j);
        int s1 = __builtin_nontemporal_load(csr + j + 1);
        int s2 = __builtin_nontemporal_load(csr + j + 2);
        int s3 = __builtin_nontemporal_load(csr + j + 3);
        int s4 = __builtin_nontemporal_load(csr + j + 4);
        int s5 = __builtin_nontemporal_load(csr + j + 5);
        int s6 = __builtin_nontemporal_load(csr + j + 6);
        int s7 = __builtin_nontemporal_load(csr + j + 7);
        float v0 = (float)hd1[(size_t)s0 * HC + f];
        float v1 = (float)hd1[(size_t)s1 * HC + f];
        float v2 = (float)hd1[(size_t)s2 * HC + f];
        float v3 = (float)hd1[(size_t)s3 * HC + f];
        float v4 = (float)hd1[(size_t)s4 * HC + f];
        float v5 = (float)hd1[(size_t)s5 * HC + f];
        float v6 = (float)hd1[(size_t)s6 * HC + f];
        float v7 = (float)hd1[(size_t)s7 * HC + f];
        acc += ((v0 + v1) + (v2 + v3)) + ((v4 + v5) + (v6 + v7));
    }
    for (; j < end; ++j)
        acc += (float)hd1[(size_t)__builtin_nontemporal_load(csr + j) * HC + f];
    float di = dinv[node];
    float h1 = fmaxf(acc * di + sb[f], 0.f);
    float a2 = 0.f;
#pragma unroll
    for (int k = 0; k < HC; ++k) {
        float hk = __shfl(h1, k, 16);
        a2 += hk * sW[k * 17 + f];
    }
    hd2[(size_t)node * HC + f] = (f16)(a2 * di);
}

// ===== layer-2 gather + fused GRU + FC: epilogue in-wave =====
__global__ void __launch_bounds__(256) gather_final_kernel(
        const f16* __restrict__ hd2, const int* __restrict__ csr,
        const int* __restrict__ row_beg, const int* __restrict__ row_end,
        const float* __restrict__ dinv, const float* __restrict__ b2,
        const float* __restrict__ w_ih, const float* __restrict__ b_ih,
        const float* __restrict__ b_hh, const float* __restrict__ Wfc,
        const float* __restrict__ bfc, float* __restrict__ out, int n) {
    __shared__ float s_wih[3 * HC * 17];   // rows j, pitch 17
    __shared__ float s_wfc[OUTC * 17];
    __shared__ float s_bih[3 * HC], s_bhh[3 * HC], s_bfc[OUTC], s_b2[HC];
    for (int i = threadIdx.x; i < 3 * HC * HC; i += 256)
        s_wih[(i >> 4) * 17 + (i & 15)] = w_ih[i];
    for (int i = threadIdx.x; i < OUTC * HC; i += 256)
        s_wfc[(i >> 4) * 17 + (i & 15)] = Wfc[i];
    if (threadIdx.x < 3 * HC) { s_bih[threadIdx.x] = b_ih[threadIdx.x]; s_bhh[threadIdx.x] = b_hh[threadIdx.x]; }
    if (threadIdx.x < OUTC) s_bfc[threadIdx.x] = bfc[threadIdx.x];
    if (threadIdx.x < HC) s_b2[threadIdx.x] = b2[threadIdx.x];
    __syncthreads();
    int t = blockIdx.x * blockDim.x + threadIdx.x;
    int node = t >> 4;
    if (node >= n) return;
    int f = t & 15;
    int beg = row_beg[node], end = row_end[node];
    float acc = (float)hd2[(size_t)node * HC + f];   // self-loop term
    int j = beg;
    for (; j + 7 < end; j += 8) {
        int s0 = __builtin_nontemporal_load(csr + j);
        int s1 = __builtin_nontemporal_load(csr + j + 1);
        int s2 = __builtin_nontemporal_load(csr + j + 2);
        int s3 = __builtin_nontemporal_load(csr + j + 3);
        int s4 = __builtin_nontemporal_load(csr + j + 4);
        int s5 = __builtin_nontemporal_load(csr + j + 5);
        int s6 = __builtin_nontemporal_load(csr + j + 6);
        int s7 = __builtin_nontemporal_load(csr + j + 7);
        float v0 = (float)hd2[(size_t)s0 * HC + f];
        float v1 = (float)hd2[(size_t)s1 * HC + f];
        float v2 = (float)hd2[(size_t)s2 * HC + f];
        float v3 = (float)hd2[(size_t)s3 * HC + f];
        float v4 = (float)hd2[(size_t)s4 * HC + f];
        float v5 = (float)hd2[(size_t)s5 * HC + f];
        float v6 = (float)hd2[(size_t)s6 * HC + f];
        float v7 = (float)hd2[(size_t)s7 * HC + f];
        acc += ((v0 + v1) + (v2 + v3)) + ((v4 + v5) + (v6 + v7));
    }
    for (; j < end; ++j)
        acc += (float)hd2[(size_t)__builtin_nontemporal_load(csr + j) * HC + f];
    float h = fmaxf(acc * dinv[node] + s_b2[f], 0.f);
    // GRU (seq=1, h0=0 => gh = b_hh): lane f computes gate row j=f
    float ir = s_bih[f], iz = s_bih[HC + f], inn = s_bih[2 * HC + f];
#pragma unroll
    for (int k = 0; k < HC; ++k) {
        float hk = __shfl(h, k, 16);
        ir  += hk * s_wih[f * 17 + k];
        iz  += hk * s_wih[(HC + f) * 17 + k];
        inn += hk * s_wih[(2 * HC + f) * 17 + k];
    }
    float r = 1.f / (1.f + __expf(-(ir + s_bhh[f])));
    float z = 1.f / (1.f + __expf(-(iz + s_bhh[HC + f])));
    float nn = tanhf(inn + r * s_bhh[2 * HC + f]);
    float hs = (1.f - z) * nn;
    // FC: lane f computes outputs o=f and o=HC+f
    float a1 = s_bfc[f], a2 = s_bfc[HC + f];
#pragma unroll
    for (int k = 0; k < HC; ++k) {
        float hk = __shfl(hs, k, 16);
        a1 += hk * s_wfc[f * 17 + k];
        a2 += hk * s_wfc[(HC + f) * 17 + k];
    }
    float* orow = out + (size_t)node * OUTC;
    __builtin_nontemporal_store(a1, orow + f);
    __builtin_nontemporal_store(a2, orow + HC + f);
}

extern "C" void kernel_launch(void* const* d_in, const int* in_sizes, int n_in,
                              void* d_out, int out_size, void* d_ws, size_t ws_size,
                              hipStream_t stream) {
    const float* x     = (const float*)d_in[0];
    const int*   ei    = (const int*)d_in[1];
    const float* W1    = (const float*)d_in[3];
    const float* b1    = (const float*)d_in[4];
    const float* W2    = (const float*)d_in[5];
    const float* b2    = (const float*)d_in[6];
    const float* w_ih  = (const float*)d_in[7];
    // d_in[8] = w_hh unused: h0 == 0 => gh = b_hh
    const float* b_ih  = (const float*)d_in[9];
    const float* b_hh  = (const float*)d_in[10];
    const float* Wfc   = (const float*)d_in[11];
    const float* bfc   = (const float*)d_in[12];
    float* out = (float*)d_out;

    const int n = in_sizes[2];          // 200000
    const int e = in_sizes[1] / 2;      // 6400000
    const int* src = ei;
    const int* dst = ei + e;
    const int nbkt = (n + 255) >> BKT_SHIFT;   // 782

    // workspace layout (16B-aligned sections)
    int*   gcur    = (int*)d_ws;                     // 1024
    int*   row_beg = gcur + 1024;                    // n
    int*   row_end = row_beg + n;                    // n
    float* dinv    = (float*)(row_end + n);          // n
    int*   csrbuf  = (int*)(dinv + n);               // nbkt*CAP
    f16*   hd1     = (f16*)(csrbuf + (size_t)nbkt * CAP);  // 16n halves (6.4 MB)
    f16*   hd2     = hd1 + (size_t)n * HC;                 // 16n halves

    const int B = 256;
    int gn   = (n + B - 1) / B;                         // 782
    int gnf  = (int)(((long long)n * HC + B - 1) / B);  // 12500
    int gbin = (e + BINS - 1) / BINS;                   // 512

    init_gcur_kernel<<<(NBMAX + B - 1) / B, B, 0, stream>>>(gcur, nbkt);
    bin_kernel<<<gbin, 512, 0, stream>>>(src, dst, gcur, csrbuf, e, nbkt);
    bucketize_kernel<<<nbkt, 512, 0, stream>>>(gcur, csrbuf, row_beg, row_end, dinv, n);

    gemm1_kernel<<<gn, B, 0, stream>>>(x, W1, dinv, hd1, n);
    gather_fuse1_kernel<<<gnf, B, 0, stream>>>(hd1, csrbuf, row_beg, row_end, dinv, b1, W2, hd2, n);
    gather_final_kernel<<<gnf, B, 0, stream>>>(hd2, csrbuf, row_beg, row_end, dinv, b2,
                                               w_ih, b_ih, b_hh, Wfc, bfc, out, n);
}

// Round 3
// 538.740 us; speedup vs baseline: 1.0242x; 1.0072x over previous
//
#include <hip/hip_runtime.h>
#include <hip/hip_fp16.h>
#include <math.h>

#define HC 16      // hidden
#define INC 128    // in_channels
#define OUTC 32    // out_channels
#define BKT_SHIFT 8            // 256 nodes per bucket
#define CAP 9216               // bucket edge capacity: E[8192] + 11 sigma
#define NBMAX 1024             // max buckets (782 actual)
#define BINS 6400              // edges per bin block (smaller: 4 blocks/CU vs 2)

typedef _Float16 f16;
typedef float vfloat2 __attribute__((ext_vector_type(2)));

// ================= CSR build: LDS-staged binning =================

__global__ void init_gcur_kernel(int* __restrict__ gcur, int nbkt) {
    int i = blockIdx.x * blockDim.x + threadIdx.x;
    if (i < nbkt) gcur[i] = i * CAP;
}

// 512 threads/block, ~38KB LDS -> 4 blocks/CU (was 2 at 64KB).
// Packed entry: (dlocal << 18) | src   (src < 2^18, dlocal < 256)
__global__ void __launch_bounds__(512) bin_kernel(
        const int* __restrict__ src, const int* __restrict__ dst,
        int* __restrict__ gcur, int* __restrict__ csrbuf, int e, int nbkt) {
    __shared__ int ent[BINS];        // 25.6 KB staging
    __shared__ int hist[NBMAX];      // counts -> local cursors
    __shared__ int off[NBMAX];       // exclusive offsets into staging
    __shared__ int gbase[NBMAX];     // reserved global bases
    __shared__ int wsum[8];          // per-wave scan partials
    int tid = threadIdx.x;
    int beg = blockIdx.x * BINS;
    int end = min(beg + BINS, e);
    int sz = end - beg;
    if (sz <= 0) return;

    for (int i = tid; i < NBMAX; i += 512) hist[i] = 0;
    __syncthreads();
    for (int i = beg + tid; i < end; i += 512)
        atomicAdd(&hist[dst[i] >> BKT_SHIFT], 1);
    __syncthreads();
    // scan: thread t owns buckets 2t, 2t+1; shfl wave-scan + cross-wave fixup
    int b0 = tid * 2;
    int c0 = hist[b0], c1 = hist[b0 + 1];
    int tsum = c0 + c1;
    int lane = tid & 63, wid = tid >> 6;
    int v = tsum;
#pragma unroll
    for (int d = 1; d < 64; d <<= 1) {
        int u = __shfl_up(v, d, 64);
        if (lane >= d) v += u;
    }
    if (lane == 63) wsum[wid] = v;
    __syncthreads();
    int wbase = 0;
#pragma unroll
    for (int w = 0; w < 8; ++w) wbase += (w < wid) ? wsum[w] : 0;
    int ex = wbase + v - tsum;       // exclusive prefix of tsum
    off[b0]     = ex;
    off[b0 + 1] = ex + c0;
    if (c0) gbase[b0]     = atomicAdd(&gcur[b0], c0);
    if (c1) gbase[b0 + 1] = atomicAdd(&gcur[b0 + 1], c1);
    hist[b0] = 0; hist[b0 + 1] = 0;
    __syncthreads();
    // group into staging
    for (int i = beg + tid; i < end; i += 512) {
        int d = dst[i];
        int b = d >> BKT_SHIFT;
        int p = off[b] + atomicAdd(&hist[b], 1);
        ent[p] = (src[i] & 0x3FFFF) | ((d & 255) << 18);
    }
    __syncthreads();
    // flush: contiguous k; per-element binary search for bucket
    for (int k0 = 0; k0 < sz; k0 += 512) {
        int k = k0 + tid;
        if (k < sz) {
            int lo = 0, hi = nbkt - 1;     // largest b with off[b] <= k
            while (lo < hi) {
                int mid = (lo + hi + 1) >> 1;
                if (off[mid] <= k) lo = mid; else hi = mid - 1;
            }
            csrbuf[gbase[lo] + (k - off[lo])] = ent[k];
        }
    }
}

// One block (512 threads) per bucket: group entries by node, emit row ranges + dinv.
__global__ void __launch_bounds__(512) bucketize_kernel(
        const int* __restrict__ gcur, int* __restrict__ csrbuf,
        int* __restrict__ row_beg, int* __restrict__ row_end,
        float* __restrict__ dinv, int n) {
    __shared__ int ent[CAP];     // 36 KB
    __shared__ int cnt[256];
    __shared__ int off[256];
    __shared__ int cur[256];
    int tid = threadIdx.x;
    int b = blockIdx.x;
    int base = b * CAP;
    int sz = gcur[b] - base;
    if (sz > CAP) sz = CAP;      // defensive (statically unreachable)
    int node0 = b << BKT_SHIFT;
    int nnodes = min(256, n - node0);
    for (int i = tid; i < sz; i += 512) ent[i] = csrbuf[base + i];
    if (tid < 256) cnt[tid] = 0;
    __syncthreads();
    for (int i = tid; i < sz; i += 512) atomicAdd(&cnt[ent[i] >> 18], 1);
    __syncthreads();
    int v = (tid < 256) ? cnt[tid] : 0;
    if (tid < 256) off[tid] = v;
    __syncthreads();
    for (int d = 1; d < 256; d <<= 1) {
        int u = (tid < 256 && tid >= d) ? off[tid - d] : 0;
        __syncthreads();
        if (tid < 256) off[tid] += u;
        __syncthreads();
    }
    if (tid < 256) {
        int excl = off[tid] - v;
        cur[tid] = excl;
        if (tid < nnodes) {
            row_beg[node0 + tid] = base + excl;
            row_end[node0 + tid] = base + excl + v;
            dinv[node0 + tid] = rsqrtf((float)v + 1.0f);   // +1 self-loop
        }
    }
    __syncthreads();
    for (int i = tid; i < sz; i += 512) {
        int p = ent[i];
        int dl = p >> 18;
        int pos = atomicAdd(&cur[dl], 1);
        csrbuf[base + pos] = p & 0x3FFFF;
    }
}

// ===== layer 1 GEMM: hd1 = (x @ W1) * dinv[node], fp16 out, LDS-tiled x =====
// Block = 256 threads: 4 tiles of 64 nodes; wave w computes feature quad w.
__global__ void __launch_bounds__(256) gemm1_kernel(
        const float* __restrict__ x, const float* __restrict__ W1,
        const float* __restrict__ dinv, f16* __restrict__ hd1, int n) {
    __shared__ float sW[INC * HC];     // 8 KB  [k][f]
    __shared__ float sx[64 * 130];     // 33.3 KB, pitch 130 (2-way alias = free)
    int tid = threadIdx.x;
    for (int i = tid; i < INC * HC; i += 256) sW[i] = W1[i];
    int l  = tid & 63;       // node within tile
    int fq = tid >> 6;       // feature quad (wave id)
    int nbase = blockIdx.x * 256;
    for (int tile = 0; tile < 4; ++tile) {
        int n0 = nbase + tile * 64;
        __syncthreads();     // protect sx before overwrite (also covers sW 1st iter)
        // stage 64x128 f32, coalesced 8B, nontemporal (read-once stream)
        for (int i = tid; i < 64 * 64; i += 256) {
            int row = i >> 6;
            int c2  = i & 63;
            if (n0 + row < n) {
                vfloat2 v = __builtin_nontemporal_load(
                    (const vfloat2*)(x + (size_t)(n0 + row) * INC) + c2);
                *(vfloat2*)&sx[row * 130 + c2 * 2] = v;
            }
        }
        __syncthreads();
        int node = n0 + l;
        if (node >= n) continue;
        const float* xr = &sx[l * 130];
        float a0 = 0.f, a1 = 0.f, a2 = 0.f, a3 = 0.f;
#pragma unroll 8
        for (int k = 0; k < INC; ++k) {
            float xv = xr[k];
            float4 w = *(const float4*)&sW[k * HC + fq * 4];  // broadcast in wave
            a0 += xv * w.x; a1 += xv * w.y; a2 += xv * w.z; a3 += xv * w.w;
        }
        float di = dinv[node];
        union { f16 h[4]; vfloat2 p; } u;
        u.h[0] = (f16)(a0 * di); u.h[1] = (f16)(a1 * di);
        u.h[2] = (f16)(a2 * di); u.h[3] = (f16)(a3 * di);
        *(vfloat2*)&hd1[(size_t)node * HC + fq * 4] = u.p;
    }
}

// ===== layer-1 gather + fused W2: software-pipelined csr address stream =====
__global__ void __launch_bounds__(256) gather_fuse1_kernel(
        const f16* __restrict__ hd1, const int* __restrict__ csr,
        const int* __restrict__ row_beg, const int* __restrict__ row_end,
        const float* __restrict__ dinv, const float* __restrict__ b1,
        const float* __restrict__ W2, f16* __restrict__ hd2, int n) {
    __shared__ float sW[HC * 17];    // pitch 17: conflict-free column reads
    __shared__ float sb[HC];
    if (threadIdx.x < HC * HC) sW[(threadIdx.x >> 4) * 17 + (threadIdx.x & 15)] = W2[threadIdx.x];
    if (threadIdx.x < HC) sb[threadIdx.x] = b1[threadIdx.x];
    __syncthreads();
    int t = blockIdx.x * blockDim.x + threadIdx.x;
    int node = t >> 4;
    if (node >= n) return;
    int f = t & 15;
    int beg = row_beg[node], end = row_end[node];
    float acc = (float)hd1[(size_t)node * HC + f];   // self-loop term
    int j = beg;
    int nb = (end - beg) >> 3;
    if (nb > 0) {
        int s0 = csr[j],     s1 = csr[j + 1], s2 = csr[j + 2], s3 = csr[j + 3];
        int s4 = csr[j + 4], s5 = csr[j + 5], s6 = csr[j + 6], s7 = csr[j + 7];
        for (int b = 1; b < nb; ++b) {
            // preload next batch's addresses (hides under gather wait)
            int t0 = csr[j + 8],  t1 = csr[j + 9],  t2 = csr[j + 10], t3 = csr[j + 11];
            int t4 = csr[j + 12], t5 = csr[j + 13], t6 = csr[j + 14], t7 = csr[j + 15];
            float v0 = (float)hd1[(size_t)s0 * HC + f];
            float v1 = (float)hd1[(size_t)s1 * HC + f];
            float v2 = (float)hd1[(size_t)s2 * HC + f];
            float v3 = (float)hd1[(size_t)s3 * HC + f];
            float v4 = (float)hd1[(size_t)s4 * HC + f];
            float v5 = (float)hd1[(size_t)s5 * HC + f];
            float v6 = (float)hd1[(size_t)s6 * HC + f];
            float v7 = (float)hd1[(size_t)s7 * HC + f];
            acc += ((v0 + v1) + (v2 + v3)) + ((v4 + v5) + (v6 + v7));
            s0 = t0; s1 = t1; s2 = t2; s3 = t3;
            s4 = t4; s5 = t5; s6 = t6; s7 = t7;
            j += 8;
        }
        float v0 = (float)hd1[(size_t)s0 * HC + f];
        float v1 = (float)hd1[(size_t)s1 * HC + f];
        float v2 = (float)hd1[(size_t)s2 * HC + f];
        float v3 = (float)hd1[(size_t)s3 * HC + f];
        float v4 = (float)hd1[(size_t)s4 * HC + f];
        float v5 = (float)hd1[(size_t)s5 * HC + f];
        float v6 = (float)hd1[(size_t)s6 * HC + f];
        float v7 = (float)hd1[(size_t)s7 * HC + f];
        acc += ((v0 + v1) + (v2 + v3)) + ((v4 + v5) + (v6 + v7));
        j += 8;
    }
    for (; j < end; ++j)
        acc += (float)hd1[(size_t)csr[j] * HC + f];
    float di = dinv[node];
    float h1 = fmaxf(acc * di + sb[f], 0.f);
    float a2 = 0.f;
#pragma unroll
    for (int k = 0; k < HC; ++k) {
        float hk = __shfl(h1, k, 16);
        a2 += hk * sW[k * 17 + f];
    }
    hd2[(size_t)node * HC + f] = (f16)(a2 * di);
}

// ===== layer-2 gather + fused GRU + FC: software-pipelined csr stream =====
__global__ void __launch_bounds__(256) gather_final_kernel(
        const f16* __restrict__ hd2, const int* __restrict__ csr,
        const int* __restrict__ row_beg, const int* __restrict__ row_end,
        const float* __restrict__ dinv, const float* __restrict__ b2,
        const float* __restrict__ w_ih, const float* __restrict__ b_ih,
        const float* __restrict__ b_hh, const float* __restrict__ Wfc,
        const float* __restrict__ bfc, float* __restrict__ out, int n) {
    __shared__ float s_wih[3 * HC * 17];   // rows j, pitch 17
    __shared__ float s_wfc[OUTC * 17];
    __shared__ float s_bih[3 * HC], s_bhh[3 * HC], s_bfc[OUTC], s_b2[HC];
    for (int i = threadIdx.x; i < 3 * HC * HC; i += 256)
        s_wih[(i >> 4) * 17 + (i & 15)] = w_ih[i];
    for (int i = threadIdx.x; i < OUTC * HC; i += 256)
        s_wfc[(i >> 4) * 17 + (i & 15)] = Wfc[i];
    if (threadIdx.x < 3 * HC) { s_bih[threadIdx.x] = b_ih[threadIdx.x]; s_bhh[threadIdx.x] = b_hh[threadIdx.x]; }
    if (threadIdx.x < OUTC) s_bfc[threadIdx.x] = bfc[threadIdx.x];
    if (threadIdx.x < HC) s_b2[threadIdx.x] = b2[threadIdx.x];
    __syncthreads();
    int t = blockIdx.x * blockDim.x + threadIdx.x;
    int node = t >> 4;
    if (node >= n) return;
    int f = t & 15;
    int beg = row_beg[node], end = row_end[node];
    float acc = (float)hd2[(size_t)node * HC + f];   // self-loop term
    int j = beg;
    int nb = (end - beg) >> 3;
    if (nb > 0) {
        int s0 = csr[j],     s1 = csr[j + 1], s2 = csr[j + 2], s3 = csr[j + 3];
        int s4 = csr[j + 4], s5 = csr[j + 5], s6 = csr[j + 6], s7 = csr[j + 7];
        for (int b = 1; b < nb; ++b) {
            int t0 = csr[j + 8],  t1 = csr[j + 9],  t2 = csr[j + 10], t3 = csr[j + 11];
            int t4 = csr[j + 12], t5 = csr[j + 13], t6 = csr[j + 14], t7 = csr[j + 15];
            float v0 = (float)hd2[(size_t)s0 * HC + f];
            float v1 = (float)hd2[(size_t)s1 * HC + f];
            float v2 = (float)hd2[(size_t)s2 * HC + f];
            float v3 = (float)hd2[(size_t)s3 * HC + f];
            float v4 = (float)hd2[(size_t)s4 * HC + f];
            float v5 = (float)hd2[(size_t)s5 * HC + f];
            float v6 = (float)hd2[(size_t)s6 * HC + f];
            float v7 = (float)hd2[(size_t)s7 * HC + f];
            acc += ((v0 + v1) + (v2 + v3)) + ((v4 + v5) + (v6 + v7));
            s0 = t0; s1 = t1; s2 = t2; s3 = t3;
            s4 = t4; s5 = t5; s6 = t6; s7 = t7;
            j += 8;
        }
        float v0 = (float)hd2[(size_t)s0 * HC + f];
        float v1 = (float)hd2[(size_t)s1 * HC + f];
        float v2 = (float)hd2[(size_t)s2 * HC + f];
        float v3 = (float)hd2[(size_t)s3 * HC + f];
        float v4 = (float)hd2[(size_t)s4 * HC + f];
        float v5 = (float)hd2[(size_t)s5 * HC + f];
        float v6 = (float)hd2[(size_t)s6 * HC + f];
        float v7 = (float)hd2[(size_t)s7 * HC + f];
        acc += ((v0 + v1) + (v2 + v3)) + ((v4 + v5) + (v6 + v7));
        j += 8;
    }
    for (; j < end; ++j)
        acc += (float)hd2[(size_t)csr[j] * HC + f];
    float h = fmaxf(acc * dinv[node] + s_b2[f], 0.f);
    // GRU (seq=1, h0=0 => gh = b_hh): lane f computes gate row j=f
    float ir = s_bih[f], iz = s_bih[HC + f], inn = s_bih[2 * HC + f];
#pragma unroll
    for (int k = 0; k < HC; ++k) {
        float hk = __shfl(h, k, 16);
        ir  += hk * s_wih[f * 17 + k];
        iz  += hk * s_wih[(HC + f) * 17 + k];
        inn += hk * s_wih[(2 * HC + f) * 17 + k];
    }
    float r = 1.f / (1.f + __expf(-(ir + s_bhh[f])));
    float z = 1.f / (1.f + __expf(-(iz + s_bhh[HC + f])));
    float nn = tanhf(inn + r * s_bhh[2 * HC + f]);
    float hs = (1.f - z) * nn;
    // FC: lane f computes outputs o=f and o=HC+f
    float a1 = s_bfc[f], a2 = s_bfc[HC + f];
#pragma unroll
    for (int k = 0; k < HC; ++k) {
        float hk = __shfl(hs, k, 16);
        a1 += hk * s_wfc[f * 17 + k];
        a2 += hk * s_wfc[(HC + f) * 17 + k];
    }
    float* orow = out + (size_t)node * OUTC;
    __builtin_nontemporal_store(a1, orow + f);
    __builtin_nontemporal_store(a2, orow + HC + f);
}

extern "C" void kernel_launch(void* const* d_in, const int* in_sizes, int n_in,
                              void* d_out, int out_size, void* d_ws, size_t ws_size,
                              hipStream_t stream) {
    const float* x     = (const float*)d_in[0];
    const int*   ei    = (const int*)d_in[1];
    const float* W1    = (const float*)d_in[3];
    const float* b1    = (const float*)d_in[4];
    const float* W2    = (const float*)d_in[5];
    const float* b2    = (const float*)d_in[6];
    const float* w_ih  = (const float*)d_in[7];
    // d_in[8] = w_hh unused: h0 == 0 => gh = b_hh
    const float* b_ih  = (const float*)d_in[9];
    const float* b_hh  = (const float*)d_in[10];
    const float* Wfc   = (const float*)d_in[11];
    const float* bfc   = (const float*)d_in[12];
    float* out = (float*)d_out;

    const int n = in_sizes[2];          // 200000
    const int e = in_sizes[1] / 2;      // 6400000
    const int* src = ei;
    const int* dst = ei + e;
    const int nbkt = (n + 255) >> BKT_SHIFT;   // 782

    // workspace layout (16B-aligned sections)
    int*   gcur    = (int*)d_ws;                     // 1024
    int*   row_beg = gcur + 1024;                    // n
    int*   row_end = row_beg + n;                    // n
    float* dinv    = (float*)(row_end + n);          // n
    int*   csrbuf  = (int*)(dinv + n);               // nbkt*CAP
    f16*   hd1     = (f16*)(csrbuf + (size_t)nbkt * CAP);  // 16n halves (6.4 MB)
    f16*   hd2     = hd1 + (size_t)n * HC;                 // 16n halves

    const int B = 256;
    int gn   = (n + B - 1) / B;                         // 782
    int gnf  = (int)(((long long)n * HC + B - 1) / B);  // 12500
    int gbin = (e + BINS - 1) / BINS;                   // 1000

    init_gcur_kernel<<<(NBMAX + B - 1) / B, B, 0, stream>>>(gcur, nbkt);
    bin_kernel<<<gbin, 512, 0, stream>>>(src, dst, gcur, csrbuf, e, nbkt);
    bucketize_kernel<<<nbkt, 512, 0, stream>>>(gcur, csrbuf, row_beg, row_end, dinv, n);

    gemm1_kernel<<<gn, B, 0, stream>>>(x, W1, dinv, hd1, n);
    gather_fuse1_kernel<<<gnf, B, 0, stream>>>(hd1, csrbuf, row_beg, row_end, dinv, b1, W2, hd2, n);
    gather_final_kernel<<<gnf, B, 0, stream>>>(hd2, csrbuf, row_beg, row_end, dinv, b2,
                                               w_ih, b_ih, b_hh, Wfc, bfc, out, n);
}

// Round 5
// 458.933 us; speedup vs baseline: 1.2023x; 1.1739x over previous
//
#include <hip/hip_runtime.h>
#include <hip/hip_fp16.h>
#include <math.h>

#define HC 16      // hidden
#define INC 128    // in_channels
#define OUTC 32    // out_channels
#define BKT_SHIFT 8            // 256 nodes per bucket
#define CAP 9216               // bucket edge capacity: E[8192] + 11 sigma
#define NBMAX 1024             // max buckets (782 actual)
#define BINS 12512             // edges per bin block (R1-proven config)

typedef _Float16 f16;
typedef _Float16 f16x8 __attribute__((ext_vector_type(8)));

// ================= CSR build: LDS-staged binning =================

__global__ void init_gcur_kernel(int* __restrict__ gcur, int nbkt) {
    int i = blockIdx.x * blockDim.x + threadIdx.x;
    if (i < nbkt) gcur[i] = i * CAP;
}

// 512 threads/block. Packed entry: (dlocal << 18) | src
__global__ void __launch_bounds__(512) bin_kernel(
        const int* __restrict__ src, const int* __restrict__ dst,
        int* __restrict__ gcur, int* __restrict__ csrbuf, int e, int nbkt) {
    __shared__ int ent[BINS];        // 50 KB staging
    __shared__ int hist[NBMAX];      // counts -> local cursors
    __shared__ int off[NBMAX];       // exclusive offsets into staging
    __shared__ int gbase[NBMAX];     // reserved global bases
    __shared__ int wsum[8];          // per-wave scan partials
    int tid = threadIdx.x;
    int beg = blockIdx.x * BINS;
    int end = min(beg + BINS, e);
    int sz = end - beg;
    if (sz <= 0) return;

    for (int i = tid; i < NBMAX; i += 512) hist[i] = 0;
    __syncthreads();
    for (int i = beg + tid; i < end; i += 512)
        atomicAdd(&hist[dst[i] >> BKT_SHIFT], 1);
    __syncthreads();
    // scan: thread t owns buckets 2t, 2t+1; shfl wave-scan + cross-wave fixup
    int b0 = tid * 2;
    int c0 = hist[b0], c1 = hist[b0 + 1];
    int tsum = c0 + c1;
    int lane = tid & 63, wid = tid >> 6;
    int v = tsum;
#pragma unroll
    for (int d = 1; d < 64; d <<= 1) {
        int u = __shfl_up(v, d, 64);
        if (lane >= d) v += u;
    }
    if (lane == 63) wsum[wid] = v;
    __syncthreads();
    int wbase = 0;
#pragma unroll
    for (int w = 0; w < 8; ++w) wbase += (w < wid) ? wsum[w] : 0;
    int ex = wbase + v - tsum;       // exclusive prefix of tsum
    off[b0]     = ex;
    off[b0 + 1] = ex + c0;
    if (c0) gbase[b0]     = atomicAdd(&gcur[b0], c0);
    if (c1) gbase[b0 + 1] = atomicAdd(&gcur[b0 + 1], c1);
    hist[b0] = 0; hist[b0 + 1] = 0;
    __syncthreads();
    // group into staging
    for (int i = beg + tid; i < end; i += 512) {
        int d = dst[i];
        int b = d >> BKT_SHIFT;
        int p = off[b] + atomicAdd(&hist[b], 1);
        ent[p] = (src[i] & 0x3FFFF) | ((d & 255) << 18);
    }
    __syncthreads();
    // flush: contiguous k; per-element binary search for bucket
    for (int k0 = 0; k0 < sz; k0 += 512) {
        int k = k0 + tid;
        if (k < sz) {
            int lo = 0, hi = nbkt - 1;     // largest b with off[b] <= k
            while (lo < hi) {
                int mid = (lo + hi + 1) >> 1;
                if (off[mid] <= k) lo = mid; else hi = mid - 1;
            }
            csrbuf[gbase[lo] + (k - off[lo])] = ent[k];
        }
    }
}

// One block (512 threads) per bucket: group entries by node, emit row ranges + dinv.
__global__ void __launch_bounds__(512) bucketize_kernel(
        const int* __restrict__ gcur, int* __restrict__ csrbuf,
        int* __restrict__ row_beg, int* __restrict__ row_end,
        float* __restrict__ dinv, int n) {
    __shared__ int ent[CAP];     // 36 KB
    __shared__ int cnt[256];
    __shared__ int off[256];
    __shared__ int cur[256];
    int tid = threadIdx.x;
    int b = blockIdx.x;
    int base = b * CAP;
    int sz = gcur[b] - base;
    if (sz > CAP) sz = CAP;      // defensive (statically unreachable)
    int node0 = b << BKT_SHIFT;
    int nnodes = min(256, n - node0);
    for (int i = tid; i < sz; i += 512) ent[i] = csrbuf[base + i];
    if (tid < 256) cnt[tid] = 0;
    __syncthreads();
    for (int i = tid; i < sz; i += 512) atomicAdd(&cnt[ent[i] >> 18], 1);
    __syncthreads();
    int v = (tid < 256) ? cnt[tid] : 0;
    if (tid < 256) off[tid] = v;
    __syncthreads();
    for (int d = 1; d < 256; d <<= 1) {
        int u = (tid < 256 && tid >= d) ? off[tid - d] : 0;
        __syncthreads();
        if (tid < 256) off[tid] += u;
        __syncthreads();
    }
    if (tid < 256) {
        int excl = off[tid] - v;
        cur[tid] = excl;
        if (tid < nnodes) {
            row_beg[node0 + tid] = base + excl;
            row_end[node0 + tid] = base + excl + v;
            dinv[node0 + tid] = rsqrtf((float)v + 1.0f);   // +1 self-loop
        }
    }
    __syncthreads();
    for (int i = tid; i < sz; i += 512) {
        int p = ent[i];
        int dl = p >> 18;
        int pos = atomicAdd(&cur[dl], 1);
        csrbuf[base + pos] = p & 0x3FFFF;
    }
}

// ================= layer 1 GEMM: hd1 = (x @ W1) * dinv[node], fp16 out ======
// (R1-proven version: one node per thread, float4 x loads, W1 in LDS)
__global__ void gemm1_kernel(const float* __restrict__ x, const float* __restrict__ W1,
                             const float* __restrict__ dinv, f16* __restrict__ hd1, int n) {
    __shared__ float sW[INC * HC];   // 8 KB
    for (int i = threadIdx.x; i < INC * HC; i += blockDim.x) sW[i] = W1[i];
    __syncthreads();
    int node = blockIdx.x * blockDim.x + threadIdx.x;
    if (node >= n) return;
    const float4* xr = (const float4*)(x + (size_t)node * INC);
    float acc[HC];
#pragma unroll
    for (int f = 0; f < HC; ++f) acc[f] = 0.f;
#pragma unroll 4
    for (int k4 = 0; k4 < INC / 4; ++k4) {
        float4 v = xr[k4];
        const float* w = &sW[k4 * 4 * HC];
#pragma unroll
        for (int f = 0; f < HC; ++f)
            acc[f] += v.x * w[f] + v.y * w[HC + f] + v.z * w[2 * HC + f] + v.w * w[3 * HC + f];
    }
    float di = dinv[node];
    union { f16 h[HC]; float4 q[2]; } u;
#pragma unroll
    for (int f = 0; f < HC; ++f) u.h[f] = (f16)(acc[f] * di);
    float4* hl = (float4*)(hd1 + (size_t)node * HC);
    hl[0] = u.q[0];
    hl[1] = u.q[1];
}

// ===== wide-load gather core: lane l of 16-lane group = (half h=l&1, slot k=l>>1)
// each lane strides edges by 8, loading 16B (8 f16) per edge -> 8x fewer VMEM
// requests than 16x2B. Returns feature-f sum (incl self-loop) in "lane f" layout.
__device__ __forceinline__ float gather_row16(
        const f16* __restrict__ hd, const int* __restrict__ csr,
        int beg, int end, int node, int f) {
    int h = f & 1;           // which 16B half
    int k = f >> 1;          // edge slot 0..7
    float a0 = 0.f, a1 = 0.f, a2 = 0.f, a3 = 0.f;
    float a4 = 0.f, a5 = 0.f, a6 = 0.f, a7 = 0.f;
    int jj = beg + k;
    if (jj < end) {
        int s = csr[jj];
        jj += 8;
        for (; jj < end; jj += 8) {
            int sn = csr[jj];   // prefetch next edge's src (hides csr latency)
            f16x8 v = *(const f16x8*)(hd + ((size_t)s << 4) + (h << 3));
            a0 += (float)v[0]; a1 += (float)v[1]; a2 += (float)v[2]; a3 += (float)v[3];
            a4 += (float)v[4]; a5 += (float)v[5]; a6 += (float)v[6]; a7 += (float)v[7];
            s = sn;
        }
        f16x8 v = *(const f16x8*)(hd + ((size_t)s << 4) + (h << 3));
        a0 += (float)v[0]; a1 += (float)v[1]; a2 += (float)v[2]; a3 += (float)v[3];
        a4 += (float)v[4]; a5 += (float)v[5]; a6 += (float)v[6]; a7 += (float)v[7];
    }
    // reduce across the 8 lanes sharing this half (xor over slot bits = lane bits 1..3)
#pragma unroll
    for (int m = 2; m <= 8; m <<= 1) {
        a0 += __shfl_xor(a0, m, 16); a1 += __shfl_xor(a1, m, 16);
        a2 += __shfl_xor(a2, m, 16); a3 += __shfl_xor(a3, m, 16);
        a4 += __shfl_xor(a4, m, 16); a5 += __shfl_xor(a5, m, 16);
        a6 += __shfl_xor(a6, m, 16); a7 += __shfl_xor(a7, m, 16);
    }
    // rearrange to "lane f holds feature f". Source-side select: lane l exports
    // element (l>>1)=k of its half (l&1)=h, i.e. feature (h*8 + k). Destination f
    // needs half f>>3, element f&7 -> source lane ((f&7)<<1)|(f>>3).
    float e = a0;
    e = (k == 1) ? a1 : e;
    e = (k == 2) ? a2 : e;
    e = (k == 3) ? a3 : e;
    e = (k == 4) ? a4 : e;
    e = (k == 5) ? a5 : e;
    e = (k == 6) ? a6 : e;
    e = (k == 7) ? a7 : e;
    float gsum = __shfl(e, ((f & 7) << 1) | (f >> 3), 16);
    // self-loop term
    return gsum + (float)hd[(size_t)node * HC + f];
}

// ===== layer-1 gather + fused W2 =====
__global__ void __launch_bounds__(256) gather_fuse1_kernel(
        const f16* __restrict__ hd1, const int* __restrict__ csr,
        const int* __restrict__ row_beg, const int* __restrict__ row_end,
        const float* __restrict__ dinv, const float* __restrict__ b1,
        const float* __restrict__ W2, f16* __restrict__ hd2, int n) {
    __shared__ float sW[HC * 17];    // pitch 17: conflict-free column reads
    __shared__ float sb[HC];
    if (threadIdx.x < HC * HC) sW[(threadIdx.x >> 4) * 17 + (threadIdx.x & 15)] = W2[threadIdx.x];
    if (threadIdx.x < HC) sb[threadIdx.x] = b1[threadIdx.x];
    __syncthreads();
    int t = blockIdx.x * blockDim.x + threadIdx.x;
    int node = t >> 4;
    if (node >= n) return;
    int f = t & 15;
    float acc = gather_row16(hd1, csr, row_beg[node], row_end[node], node, f);
    float di = dinv[node];
    float h1 = fmaxf(acc * di + sb[f], 0.f);
    float a2 = 0.f;
#pragma unroll
    for (int k = 0; k < HC; ++k) {
        float hk = __shfl(h1, k, 16);
        a2 += hk * sW[k * 17 + f];
    }
    hd2[(size_t)node * HC + f] = (f16)(a2 * di);
}

// ===== layer-2 gather + fused GRU + FC =====
__global__ void __launch_bounds__(256) gather_final_kernel(
        const f16* __restrict__ hd2, const int* __restrict__ csr,
        const int* __restrict__ row_beg, const int* __restrict__ row_end,
        const float* __restrict__ dinv, const float* __restrict__ b2,
        const float* __restrict__ w_ih, const float* __restrict__ b_ih,
        const float* __restrict__ b_hh, const float* __restrict__ Wfc,
        const float* __restrict__ bfc, float* __restrict__ out, int n) {
    __shared__ float s_wih[3 * HC * 17];   // rows j, pitch 17
    __shared__ float s_wfc[OUTC * 17];
    __shared__ float s_bih[3 * HC], s_bhh[3 * HC], s_bfc[OUTC], s_b2[HC];
    for (int i = threadIdx.x; i < 3 * HC * HC; i += 256)
        s_wih[(i >> 4) * 17 + (i & 15)] = w_ih[i];
    for (int i = threadIdx.x; i < OUTC * HC; i += 256)
        s_wfc[(i >> 4) * 17 + (i & 15)] = Wfc[i];
    if (threadIdx.x < 3 * HC) { s_bih[threadIdx.x] = b_ih[threadIdx.x]; s_bhh[threadIdx.x] = b_hh[threadIdx.x]; }
    if (threadIdx.x < OUTC) s_bfc[threadIdx.x] = bfc[threadIdx.x];
    if (threadIdx.x < HC) s_b2[threadIdx.x] = b2[threadIdx.x];
    __syncthreads();
    int t = blockIdx.x * blockDim.x + threadIdx.x;
    int node = t >> 4;
    if (node >= n) return;
    int f = t & 15;
    float acc = gather_row16(hd2, csr, row_beg[node], row_end[node], node, f);
    float h = fmaxf(acc * dinv[node] + s_b2[f], 0.f);
    // GRU (seq=1, h0=0 => gh = b_hh): lane f computes gate row j=f
    float ir = s_bih[f], iz = s_bih[HC + f], inn = s_bih[2 * HC + f];
#pragma unroll
    for (int k = 0; k < HC; ++k) {
        float hk = __shfl(h, k, 16);
        ir  += hk * s_wih[f * 17 + k];
        iz  += hk * s_wih[(HC + f) * 17 + k];
        inn += hk * s_wih[(2 * HC + f) * 17 + k];
    }
    float r = 1.f / (1.f + __expf(-(ir + s_bhh[f])));
    float z = 1.f / (1.f + __expf(-(iz + s_bhh[HC + f])));
    float nn = tanhf(inn + r * s_bhh[2 * HC + f]);
    float hs = (1.f - z) * nn;
    // FC: lane f computes outputs o=f and o=HC+f
    float a1 = s_bfc[f], a2 = s_bfc[HC + f];
#pragma unroll
    for (int k = 0; k < HC; ++k) {
        float hk = __shfl(hs, k, 16);
        a1 += hk * s_wfc[f * 17 + k];
        a2 += hk * s_wfc[(HC + f) * 17 + k];
    }
    float* orow = out + (size_t)node * OUTC;
    __builtin_nontemporal_store(a1, orow + f);
    __builtin_nontemporal_store(a2, orow + HC + f);
}

extern "C" void kernel_launch(void* const* d_in, const int* in_sizes, int n_in,
                              void* d_out, int out_size, void* d_ws, size_t ws_size,
                              hipStream_t stream) {
    const float* x     = (const float*)d_in[0];
    const int*   ei    = (const int*)d_in[1];
    const float* W1    = (const float*)d_in[3];
    const float* b1    = (const float*)d_in[4];
    const float* W2    = (const float*)d_in[5];
    const float* b2    = (const float*)d_in[6];
    const float* w_ih  = (const float*)d_in[7];
    // d_in[8] = w_hh unused: h0 == 0 => gh = b_hh
    const float* b_ih  = (const float*)d_in[9];
    const float* b_hh  = (const float*)d_in[10];
    const float* Wfc   = (const float*)d_in[11];
    const float* bfc   = (const float*)d_in[12];
    float* out = (float*)d_out;

    const int n = in_sizes[2];          // 200000
    const int e = in_sizes[1] / 2;      // 6400000
    const int* src = ei;
    const int* dst = ei + e;
    const int nbkt = (n + 255) >> BKT_SHIFT;   // 782

    // workspace layout (16B-aligned sections)
    int*   gcur    = (int*)d_ws;                     // 1024
    int*   row_beg = gcur + 1024;                    // n
    int*   row_end = row_beg + n;                    // n
    float* dinv    = (float*)(row_end + n);          // n
    int*   csrbuf  = (int*)(dinv + n);               // nbkt*CAP
    f16*   hd1     = (f16*)(csrbuf + (size_t)nbkt * CAP);  // 16n halves (6.4 MB)
    f16*   hd2     = hd1 + (size_t)n * HC;                 // 16n halves

    const int B = 256;
    int gn   = (n + B - 1) / B;                         // 782
    int gnf  = (int)(((long long)n * HC + B - 1) / B);  // 12500
    int gbin = (e + BINS - 1) / BINS;                   // 512

    init_gcur_kernel<<<(NBMAX + B - 1) / B, B, 0, stream>>>(gcur, nbkt);
    bin_kernel<<<gbin, 512, 0, stream>>>(src, dst, gcur, csrbuf, e, nbkt);
    bucketize_kernel<<<nbkt, 512, 0, stream>>>(gcur, csrbuf, row_beg, row_end, dinv, n);

    gemm1_kernel<<<gn, B, 0, stream>>>(x, W1, dinv, hd1, n);
    gather_fuse1_kernel<<<gnf, B, 0, stream>>>(hd1, csrbuf, row_beg, row_end, dinv, b1, W2, hd2, n);
    gather_final_kernel<<<gnf, B, 0, stream>>>(hd2, csrbuf, row_beg, row_end, dinv, b2,
                                               w_ih, b_ih, b_hh, Wfc, bfc, out, n);
}

// Round 6
// 448.236 us; speedup vs baseline: 1.2310x; 1.0239x over previous
//
#include <hip/hip_runtime.h>
#include <hip/hip_fp16.h>
#include <math.h>

#define HC 16      // hidden
#define INC 128    // in_channels
#define OUTC 32    // out_channels
#define BKT_SHIFT 8            // 256 nodes per bucket
#define CAP 9216               // bucket edge capacity: E[8192] + 11 sigma
#define NBMAX 1024             // max buckets (782 actual)
#define BINS 12288             // 24 edges/thread * 512 threads, exact
#define EPT 24                 // edges per thread (register-stashed)

typedef _Float16 f16;
typedef _Float16 f16x8 __attribute__((ext_vector_type(8)));

// ================= CSR build: LDS-staged binning =================

__global__ void init_gcur_kernel(int* __restrict__ gcur, int nbkt) {
    int i = blockIdx.x * blockDim.x + threadIdx.x;
    if (i < nbkt) gcur[i] = i * CAP;
}

// 512 threads/block. Packed entry: (dlocal << 18) | src
// v2: edges register-stashed (one global read pass), per-bucket flush
// (no binary search -> no dependent LDS chains).
__global__ void __launch_bounds__(512) bin_kernel(
        const int* __restrict__ src, const int* __restrict__ dst,
        int* __restrict__ gcur, int* __restrict__ csrbuf, int e, int nbkt) {
    __shared__ int ent[BINS];        // 48 KB staging
    __shared__ int hist[NBMAX];      // counts -> local cursors (reused)
    __shared__ int off[NBMAX];       // exclusive offsets into staging
    __shared__ int gbase[NBMAX];     // reserved global bases
    __shared__ int wsum[8];          // per-wave scan partials
    int tid = threadIdx.x;
    int beg = blockIdx.x * BINS;
    int end = min(beg + BINS, e);
    if (end <= beg) return;

    // phase A: stash edges in registers (statically indexed), histogram
    int myd[EPT], mys[EPT];
#pragma unroll
    for (int u = 0; u < EPT; ++u) {
        int i = beg + u * 512 + tid;
        myd[u] = (i < end) ? dst[i] : -1;
        mys[u] = (i < end) ? src[i] : 0;
    }
    for (int i = tid; i < NBMAX; i += 512) hist[i] = 0;
    __syncthreads();
#pragma unroll
    for (int u = 0; u < EPT; ++u)
        if (myd[u] >= 0) atomicAdd(&hist[myd[u] >> BKT_SHIFT], 1);
    __syncthreads();

    // phase B: scan (thread t owns buckets 2t,2t+1); shfl wave-scan + fixup
    int b0 = tid * 2;
    int c0 = hist[b0], c1 = hist[b0 + 1];
    int tsum = c0 + c1;
    int lane = tid & 63, wid = tid >> 6;
    int v = tsum;
#pragma unroll
    for (int d = 1; d < 64; d <<= 1) {
        int u = __shfl_up(v, d, 64);
        if (lane >= d) v += u;
    }
    if (lane == 63) wsum[wid] = v;
    __syncthreads();
    int wbase = 0;
#pragma unroll
    for (int w = 0; w < 8; ++w) wbase += (w < wid) ? wsum[w] : 0;
    int ex = wbase + v - tsum;       // exclusive prefix of tsum
    off[b0]     = ex;
    off[b0 + 1] = ex + c0;
    if (c0) gbase[b0]     = atomicAdd(&gcur[b0], c0);
    if (c1) gbase[b0 + 1] = atomicAdd(&gcur[b0 + 1], c1);
    hist[b0] = 0; hist[b0 + 1] = 0;   // reuse as cursors
    __syncthreads();

    // phase C: group into staging from registers (no global re-read)
#pragma unroll
    for (int u = 0; u < EPT; ++u) {
        int d = myd[u];
        if (d >= 0) {
            int b = d >> BKT_SHIFT;
            int p = off[b] + atomicAdd(&hist[b], 1);
            ent[p] = (mys[u] & 0x3FFFF) | ((d & 255) << 18);
        }
    }
    __syncthreads();

    // phase D: per-bucket flush; 16-lane group per bucket, contiguous runs
    int grp = tid >> 4;              // 32 groups
    int gl  = tid & 15;
    for (int b = grp; b < nbkt; b += 32) {
        int o = off[b];
        int c = off[b + 1] - o;      // off[nbkt] == sz (hist beyond nbkt is 0)
        if (c <= 0) continue;
        int g = gbase[b];
        for (int k = gl; k < c; k += 16)
            csrbuf[g + k] = ent[o + k];
    }
}

// One block (512 threads) per bucket: group entries by node, emit row ranges + dinv.
__global__ void __launch_bounds__(512) bucketize_kernel(
        const int* __restrict__ gcur, int* __restrict__ csrbuf,
        int* __restrict__ row_beg, int* __restrict__ row_end,
        float* __restrict__ dinv, int n) {
    __shared__ int ent[CAP];     // 36 KB
    __shared__ int cnt[256];
    __shared__ int off[256];
    __shared__ int cur[256];
    __shared__ int wsum2[4];
    int tid = threadIdx.x;
    int b = blockIdx.x;
    int base = b * CAP;
    int sz = gcur[b] - base;
    if (sz > CAP) sz = CAP;      // defensive (statically unreachable)
    int node0 = b << BKT_SHIFT;
    int nnodes = min(256, n - node0);
    for (int i = tid; i < sz; i += 512) ent[i] = csrbuf[base + i];
    if (tid < 256) cnt[tid] = 0;
    __syncthreads();
    for (int i = tid; i < sz; i += 512) atomicAdd(&cnt[ent[i] >> 18], 1);
    __syncthreads();
    // scan over 256 node-counts: shfl wave-scan (4 active waves) + fixup
    int v = (tid < 256) ? cnt[tid] : 0;
    int lane = tid & 63, w = tid >> 6;
    int vv = v;
#pragma unroll
    for (int d = 1; d < 64; d <<= 1) {
        int u = __shfl_up(vv, d, 64);
        if (lane >= d) vv += u;
    }
    if (tid < 256 && lane == 63) wsum2[w] = vv;
    __syncthreads();
    if (tid < 256) {
        int wb = 0;
#pragma unroll
        for (int w2 = 0; w2 < 4; ++w2) wb += (w2 < w) ? wsum2[w2] : 0;
        int incl = wb + vv;
        int excl = incl - v;
        cur[tid] = excl;
        if (tid < nnodes) {
            row_beg[node0 + tid] = base + excl;
            row_end[node0 + tid] = base + excl + v;
            dinv[node0 + tid] = rsqrtf((float)v + 1.0f);   // +1 self-loop
        }
    }
    __syncthreads();
    for (int i = tid; i < sz; i += 512) {
        int p = ent[i];
        int dl = p >> 18;
        int pos = atomicAdd(&cur[dl], 1);
        csrbuf[base + pos] = p & 0x3FFFF;
    }
}

// ================= layer 1 GEMM: hd1 = (x @ W1) * dinv[node], fp16 out ======
__global__ void gemm1_kernel(const float* __restrict__ x, const float* __restrict__ W1,
                             const float* __restrict__ dinv, f16* __restrict__ hd1, int n) {
    __shared__ float sW[INC * HC];   // 8 KB
    for (int i = threadIdx.x; i < INC * HC; i += blockDim.x) sW[i] = W1[i];
    __syncthreads();
    int node = blockIdx.x * blockDim.x + threadIdx.x;
    if (node >= n) return;
    const float4* xr = (const float4*)(x + (size_t)node * INC);
    float acc[HC];
#pragma unroll
    for (int f = 0; f < HC; ++f) acc[f] = 0.f;
#pragma unroll 4
    for (int k4 = 0; k4 < INC / 4; ++k4) {
        float4 v = xr[k4];
        const float* w = &sW[k4 * 4 * HC];
#pragma unroll
        for (int f = 0; f < HC; ++f)
            acc[f] += v.x * w[f] + v.y * w[HC + f] + v.z * w[2 * HC + f] + v.w * w[3 * HC + f];
    }
    float di = dinv[node];
    union { f16 h[HC]; float4 q[2]; } u;
#pragma unroll
    for (int f = 0; f < HC; ++f) u.h[f] = (f16)(acc[f] * di);
    float4* hl = (float4*)(hd1 + (size_t)node * HC);
    hl[0] = u.q[0];
    hl[1] = u.q[1];
}

// ===== wide-load gather core: lane l of 16-lane group = (half h=l&1, slot k=l>>1)
// each lane strides edges by 8, loading 16B (8 f16) per edge -> 8x fewer VMEM
// requests than 16x2B. Returns feature-f sum (incl self-loop) in "lane f" layout.
__device__ __forceinline__ float gather_row16(
        const f16* __restrict__ hd, const int* __restrict__ csr,
        int beg, int end, int node, int f) {
    int h = f & 1;           // which 16B half
    int k = f >> 1;          // edge slot 0..7
    float a0 = 0.f, a1 = 0.f, a2 = 0.f, a3 = 0.f;
    float a4 = 0.f, a5 = 0.f, a6 = 0.f, a7 = 0.f;
    int jj = beg + k;
    if (jj < end) {
        int s = csr[jj];
        jj += 8;
        for (; jj < end; jj += 8) {
            int sn = csr[jj];   // prefetch next edge's src (hides csr latency)
            f16x8 v = *(const f16x8*)(hd + ((size_t)s << 4) + (h << 3));
            a0 += (float)v[0]; a1 += (float)v[1]; a2 += (float)v[2]; a3 += (float)v[3];
            a4 += (float)v[4]; a5 += (float)v[5]; a6 += (float)v[6]; a7 += (float)v[7];
            s = sn;
        }
        f16x8 v = *(const f16x8*)(hd + ((size_t)s << 4) + (h << 3));
        a0 += (float)v[0]; a1 += (float)v[1]; a2 += (float)v[2]; a3 += (float)v[3];
        a4 += (float)v[4]; a5 += (float)v[5]; a6 += (float)v[6]; a7 += (float)v[7];
    }
    // reduce across the 8 lanes sharing this half (xor over slot bits = lane bits 1..3)
#pragma unroll
    for (int m = 2; m <= 8; m <<= 1) {
        a0 += __shfl_xor(a0, m, 16); a1 += __shfl_xor(a1, m, 16);
        a2 += __shfl_xor(a2, m, 16); a3 += __shfl_xor(a3, m, 16);
        a4 += __shfl_xor(a4, m, 16); a5 += __shfl_xor(a5, m, 16);
        a6 += __shfl_xor(a6, m, 16); a7 += __shfl_xor(a7, m, 16);
    }
    // rearrange to "lane f holds feature f". Source-side select: lane l exports
    // element (l>>1)=k of its half (l&1)=h, i.e. feature (h*8 + k). Destination f
    // needs half f>>3, element f&7 -> source lane ((f&7)<<1)|(f>>3).
    float e = a0;
    e = (k == 1) ? a1 : e;
    e = (k == 2) ? a2 : e;
    e = (k == 3) ? a3 : e;
    e = (k == 4) ? a4 : e;
    e = (k == 5) ? a5 : e;
    e = (k == 6) ? a6 : e;
    e = (k == 7) ? a7 : e;
    float gsum = __shfl(e, ((f & 7) << 1) | (f >> 3), 16);
    // self-loop term
    return gsum + (float)hd[(size_t)node * HC + f];
}

// ===== layer-1 gather + fused W2 =====
__global__ void __launch_bounds__(256) gather_fuse1_kernel(
        const f16* __restrict__ hd1, const int* __restrict__ csr,
        const int* __restrict__ row_beg, const int* __restrict__ row_end,
        const float* __restrict__ dinv, const float* __restrict__ b1,
        const float* __restrict__ W2, f16* __restrict__ hd2, int n) {
    __shared__ float sW[HC * 17];    // pitch 17: conflict-free column reads
    __shared__ float sb[HC];
    if (threadIdx.x < HC * HC) sW[(threadIdx.x >> 4) * 17 + (threadIdx.x & 15)] = W2[threadIdx.x];
    if (threadIdx.x < HC) sb[threadIdx.x] = b1[threadIdx.x];
    __syncthreads();
    int t = blockIdx.x * blockDim.x + threadIdx.x;
    int node = t >> 4;
    if (node >= n) return;
    int f = t & 15;
    float acc = gather_row16(hd1, csr, row_beg[node], row_end[node], node, f);
    float di = dinv[node];
    float h1 = fmaxf(acc * di + sb[f], 0.f);
    float a2 = 0.f;
#pragma unroll
    for (int k = 0; k < HC; ++k) {
        float hk = __shfl(h1, k, 16);
        a2 += hk * sW[k * 17 + f];
    }
    hd2[(size_t)node * HC + f] = (f16)(a2 * di);
}

// ===== layer-2 gather + fused GRU + FC =====
__global__ void __launch_bounds__(256) gather_final_kernel(
        const f16* __restrict__ hd2, const int* __restrict__ csr,
        const int* __restrict__ row_beg, const int* __restrict__ row_end,
        const float* __restrict__ dinv, const float* __restrict__ b2,
        const float* __restrict__ w_ih, const float* __restrict__ b_ih,
        const float* __restrict__ b_hh, const float* __restrict__ Wfc,
        const float* __restrict__ bfc, float* __restrict__ out, int n) {
    __shared__ float s_wih[3 * HC * 17];   // rows j, pitch 17
    __shared__ float s_wfc[OUTC * 17];
    __shared__ float s_bih[3 * HC], s_bhh[3 * HC], s_bfc[OUTC], s_b2[HC];
    for (int i = threadIdx.x; i < 3 * HC * HC; i += 256)
        s_wih[(i >> 4) * 17 + (i & 15)] = w_ih[i];
    for (int i = threadIdx.x; i < OUTC * HC; i += 256)
        s_wfc[(i >> 4) * 17 + (i & 15)] = Wfc[i];
    if (threadIdx.x < 3 * HC) { s_bih[threadIdx.x] = b_ih[threadIdx.x]; s_bhh[threadIdx.x] = b_hh[threadIdx.x]; }
    if (threadIdx.x < OUTC) s_bfc[threadIdx.x] = bfc[threadIdx.x];
    if (threadIdx.x < HC) s_b2[threadIdx.x] = b2[threadIdx.x];
    __syncthreads();
    int t = blockIdx.x * blockDim.x + threadIdx.x;
    int node = t >> 4;
    if (node >= n) return;
    int f = t & 15;
    float acc = gather_row16(hd2, csr, row_beg[node], row_end[node], node, f);
    float h = fmaxf(acc * dinv[node] + s_b2[f], 0.f);
    // GRU (seq=1, h0=0 => gh = b_hh): lane f computes gate row j=f
    float ir = s_bih[f], iz = s_bih[HC + f], inn = s_bih[2 * HC + f];
#pragma unroll
    for (int k = 0; k < HC; ++k) {
        float hk = __shfl(h, k, 16);
        ir  += hk * s_wih[f * 17 + k];
        iz  += hk * s_wih[(HC + f) * 17 + k];
        inn += hk * s_wih[(2 * HC + f) * 17 + k];
    }
    float r = 1.f / (1.f + __expf(-(ir + s_bhh[f])));
    float z = 1.f / (1.f + __expf(-(iz + s_bhh[HC + f])));
    float nn = tanhf(inn + r * s_bhh[2 * HC + f]);
    float hs = (1.f - z) * nn;
    // FC: lane f computes outputs o=f and o=HC+f
    float a1 = s_bfc[f], a2 = s_bfc[HC + f];
#pragma unroll
    for (int k = 0; k < HC; ++k) {
        float hk = __shfl(hs, k, 16);
        a1 += hk * s_wfc[f * 17 + k];
        a2 += hk * s_wfc[(HC + f) * 17 + k];
    }
    float* orow = out + (size_t)node * OUTC;
    __builtin_nontemporal_store(a1, orow + f);
    __builtin_nontemporal_store(a2, orow + HC + f);
}

extern "C" void kernel_launch(void* const* d_in, const int* in_sizes, int n_in,
                              void* d_out, int out_size, void* d_ws, size_t ws_size,
                              hipStream_t stream) {
    const float* x     = (const float*)d_in[0];
    const int*   ei    = (const int*)d_in[1];
    const float* W1    = (const float*)d_in[3];
    const float* b1    = (const float*)d_in[4];
    const float* W2    = (const float*)d_in[5];
    const float* b2    = (const float*)d_in[6];
    const float* w_ih  = (const float*)d_in[7];
    // d_in[8] = w_hh unused: h0 == 0 => gh = b_hh
    const float* b_ih  = (const float*)d_in[9];
    const float* b_hh  = (const float*)d_in[10];
    const float* Wfc   = (const float*)d_in[11];
    const float* bfc   = (const float*)d_in[12];
    float* out = (float*)d_out;

    const int n = in_sizes[2];          // 200000
    const int e = in_sizes[1] / 2;      // 6400000
    const int* src = ei;
    const int* dst = ei + e;
    const int nbkt = (n + 255) >> BKT_SHIFT;   // 782

    // workspace layout (16B-aligned sections)
    int*   gcur    = (int*)d_ws;                     // 1024
    int*   row_beg = gcur + 1024;                    // n
    int*   row_end = row_beg + n;                    // n
    float* dinv    = (float*)(row_end + n);          // n
    int*   csrbuf  = (int*)(dinv + n);               // nbkt*CAP
    f16*   hd1     = (f16*)(csrbuf + (size_t)nbkt * CAP);  // 16n halves (6.4 MB)
    f16*   hd2     = hd1 + (size_t)n * HC;                 // 16n halves

    const int B = 256;
    int gn   = (n + B - 1) / B;                         // 782
    int gnf  = (int)(((long long)n * HC + B - 1) / B);  // 12500
    int gbin = (e + BINS - 1) / BINS;                   // 521

    init_gcur_kernel<<<(NBMAX + B - 1) / B, B, 0, stream>>>(gcur, nbkt);
    bin_kernel<<<gbin, 512, 0, stream>>>(src, dst, gcur, csrbuf, e, nbkt);
    bucketize_kernel<<<nbkt, 512, 0, stream>>>(gcur, csrbuf, row_beg, row_end, dinv, n);

    gemm1_kernel<<<gn, B, 0, stream>>>(x, W1, dinv, hd1, n);
    gather_fuse1_kernel<<<gnf, B, 0, stream>>>(hd1, csrbuf, row_beg, row_end, dinv, b1, W2, hd2, n);
    gather_final_kernel<<<gnf, B, 0, stream>>>(hd2, csrbuf, row_beg, row_end, dinv, b2,
                                               w_ih, b_ih, b_hh, Wfc, bfc, out, n);
}